// Round 7
// baseline (1547.692 us; speedup 1.0000x reference)
//
#include <hip/hip_runtime.h>
#include <math.h>

#define S 32
#define T 32
#define B 64
#define H 256
#define MSZ 65536   // elements per swizzled bf16 matrix [8 kt][256 col][32 kk]
#define ROWSP 16
#define FPAD 16     // ints per flag slot (64 B line)

typedef __attribute__((ext_vector_type(8))) short s16x8;
typedef __attribute__((ext_vector_type(4))) float f32x4;

__device__ inline unsigned short f2b(float f){
    unsigned u = __builtin_bit_cast(unsigned, f);
    u += 0x7fffu + ((u >> 16) & 1u);          // RNE
    return (unsigned short)(u >> 16);
}
__device__ inline float b2f(unsigned short s){
    unsigned u = ((unsigned)s) << 16;
    return __builtin_bit_cast(float, u);
}
__device__ inline float tanh_fast(float x){
    float e = __builtin_amdgcn_exp2f(x * 2.8853900817779268f);
    float r = __builtin_amdgcn_rcpf(e + 1.0f);
    return fmaf(-2.0f, r, 1.0f);
}
__device__ inline void pollone(const int* f){
    while (__hip_atomic_load(f, __ATOMIC_RELAXED, __HIP_MEMORY_SCOPE_AGENT) == 0)
        __builtin_amdgcn_s_sleep(2);
    asm volatile("" ::: "memory");
}
// A fragment for mfma_f32_16x16x32_bf16 from row-major f32 (fallback path)
__device__ inline s16x8 make_afrag(const float* __restrict__ M, int arow, int k0){
    const float* p = M + arow * H + k0;
    float4 x = *(const float4*)(p);
    float4 y = *(const float4*)(p + 4);
    s16x8 r;
    r[0]=(short)f2b(x.x); r[1]=(short)f2b(x.y); r[2]=(short)f2b(x.z); r[3]=(short)f2b(x.w);
    r[4]=(short)f2b(y.x); r[5]=(short)f2b(y.y); r[6]=(short)f2b(y.z); r[7]=(short)f2b(y.w);
    return r;
}

// ---------------- prep: swizzle U (both depths, top/left) + W[1] to bf16 ----
// Bsw[m][kt][c][kk] = M_m[kt*32+kk][c];  m: 0=U0t 1=U0l 2=U1t 3=U1l 4=W1
__global__ __launch_bounds__(256) void prep_kernel(
    const float* __restrict__ U, const float* __restrict__ W,
    unsigned short* __restrict__ Bsw)
{
    int t = blockIdx.x * 256 + threadIdx.x;
    if (t >= 5 * MSZ) return;
    int m  = t >> 16;
    int r  = t & 65535;
    int kt = r >> 13;
    int r2 = r & 8191;
    int c  = r2 >> 5;
    int kk = r2 & 31;
    int krow = kt * 32 + kk;
    float v;
    if (m < 4){ int d = m >> 1, ope = m & 1; v = U[((size_t)d*2*H + ope*H + krow)*H + c]; }
    else      { v = W[((size_t)H + krow)*H + c]; }   // W[1]
    Bsw[t] = f2b(v);
}

// ---------------- depth-0 projections (bf16 out): sxw = src@W0, tyw = trg@W0
__global__ __launch_bounds__(256) void proj0b_kernel(
    const float* __restrict__ src, const float* __restrict__ trg,
    const float* __restrict__ W0, unsigned short* __restrict__ sxw,
    unsigned short* __restrict__ tyw)
{
    const int c = threadIdx.x;
    int gr0 = blockIdx.x * ROWSP;
    const float* inp; unsigned short* outp; int r0;
    if (gr0 < S * B) { inp = src; outp = sxw; r0 = gr0; }
    else             { inp = trg; outp = tyw; r0 = gr0 - S * B; }

    float acc[ROWSP];
#pragma unroll
    for (int rr = 0; rr < ROWSP; ++rr) acc[rr] = 0.f;
    for (int k = 0; k < H; ++k) {
        float wv = W0[k * H + c];
#pragma unroll
        for (int rr = 0; rr < ROWSP; ++rr)
            acc[rr] = fmaf(inp[(size_t)(r0 + rr) * H + k], wv, acc[rr]);
    }
#pragma unroll
    for (int rr = 0; rr < ROWSP; ++rr)
        outp[(size_t)(r0 + rr) * H + c] = f2b(acc[rr]);
}

__global__ __launch_bounds__(256) void zeroflags_kernel(int* flags, int n){
    int t = blockIdx.x * 256 + threadIdx.x;
    if (t < n) flags[t] = 0;
}

// ---------------- persistent dataflow: one block per (depth, row) ----------
// 64 blocks x 512 thr. blk 0..31 = depth0 row, 32..63 = depth1 row.
// Each wave owns 32 cols (2 col-tiles). Left dep internal via LDS.
// Flags (1 word, 64B padded): f0 = hx0 ready; g0 = xw1/yw1 proj ready; f1 = hx1.
// LDS: [0,32K) own-left hx bf16 [64][512B swz]; [32K,64K) top staging / hy.
__global__ __launch_bounds__(512, 1) void grid_kernel(
    const unsigned short* __restrict__ Bsw,
    const unsigned short* __restrict__ sxwb,
    const unsigned short* __restrict__ tywb,
    const float* __restrict__ bvec,
    float* __restrict__ out,
    int* __restrict__ flags)
{
    __shared__ char lds[65536];

    const int blk   = blockIdx.x;
    const int depth = blk >> 5;
    const int i     = blk & 31;

    const int tid  = threadIdx.x;
    const int lane = tid & 63;
    const int wv   = tid >> 6;          // wave 0..7, owns cols [wv*32, wv*32+32)
    const int colq = lane & 15;
    const int hi   = lane >> 4;
    const int kk0  = hi * 8;
    const int hi16 = hi * 16;
    const int lswz = (colq & 7) << 4;   // A-frag read swizzle
    const int c0   = wv * 32 + colq;    // col for ct=0; ct=1 -> +16

    const int srow = tid >> 3;          // staging row 0..63
    const int cb   = (tid & 7) * 32;    // staging col base (32 f32)
    const int swzS = (srow & 7) << 4;

    int* f0 = flags;
    int* g0 = flags + S*T*FPAD;
    int* f1 = flags + 2*S*T*FPAD;

    const size_t CH_ = (size_t)B * H;
#define OPTR(dd,ii,jj,cc) (out + ((((size_t)(dd)*S + (ii))*T + (jj))*2 + (cc)) * CH_)

// stage 64x256 f32 -> bf16 LDS [row][512B], XOR-swizzled
#define STAGE(BASE, SP) do { \
    const float* _p = (SP) + (size_t)srow * H + cb; \
    _Pragma("unroll") \
    for (int _l = 0; _l < 4; ++_l) { \
        float4 _a = *(const float4*)(_p + _l*8); \
        float4 _b = *(const float4*)(_p + _l*8 + 4); \
        uint4 _g; \
        _g.x = f2b(_a.x) | ((unsigned)f2b(_a.y) << 16); \
        _g.y = f2b(_a.z) | ((unsigned)f2b(_a.w) << 16); \
        _g.z = f2b(_b.x) | ((unsigned)f2b(_b.y) << 16); \
        _g.w = f2b(_b.z) | ((unsigned)f2b(_b.w) << 16); \
        *(uint4*)(lds + (BASE) + srow*512 + (((cb*2) + _l*16) ^ swzS)) = _g; \
    } } while(0)

#define AFRAG(BASE, RT, KT) (*(const s16x8*)(lds + (BASE) + ((RT)*16 + colq)*512 + ((((KT)*64) + hi16) ^ lswz)))

// 64 MFMAs: acc[rt][ct] += A(BASE) x BF[kt][ct]
#define MMPHASE(BASE, BF, ACC) do { \
    _Pragma("unroll") \
    for (int _kt = 0; _kt < 8; ++_kt) { \
        s16x8 _a0 = AFRAG(BASE, 0, _kt), _a1 = AFRAG(BASE, 1, _kt); \
        s16x8 _a2 = AFRAG(BASE, 2, _kt), _a3 = AFRAG(BASE, 3, _kt); \
        _Pragma("unroll") \
        for (int _ct = 0; _ct < 2; ++_ct) { \
            ACC[0][_ct] = __builtin_amdgcn_mfma_f32_16x16x32_bf16(_a0, BF[_kt][_ct], ACC[0][_ct], 0, 0, 0); \
            ACC[1][_ct] = __builtin_amdgcn_mfma_f32_16x16x32_bf16(_a1, BF[_kt][_ct], ACC[1][_ct], 0, 0, 0); \
            ACC[2][_ct] = __builtin_amdgcn_mfma_f32_16x16x32_bf16(_a2, BF[_kt][_ct], ACC[2][_ct], 0, 0, 0); \
            ACC[3][_ct] = __builtin_amdgcn_mfma_f32_16x16x32_bf16(_a3, BF[_kt][_ct], ACC[3][_ct], 0, 0, 0); \
        } \
    } } while(0)

    if (depth == 0) {
        s16x8 bfT[8][2], bfL[8][2];
#pragma unroll
        for (int kt = 0; kt < 8; ++kt)
#pragma unroll
            for (int ct = 0; ct < 2; ++ct) {
                int o = (kt * H + c0 + ct*16) * 32 + kk0;
                bfT[kt][ct] = *(const s16x8*)(Bsw + o);
                bfL[kt][ct] = *(const s16x8*)(Bsw + (size_t)MSZ + o);
            }
        const float bb0 = bvec[c0], bb1 = bvec[c0 + 16];
        unsigned short xwr[32];
        {
            const unsigned short* xwp = sxwb + (size_t)i * CH_;
#pragma unroll
            for (int rt = 0; rt < 4; ++rt)
#pragma unroll
                for (int ct = 0; ct < 2; ++ct)
#pragma unroll
                    for (int q = 0; q < 4; ++q)
                        xwr[(rt*4+q)*2+ct] = xwp[(size_t)(rt*16 + hi*4 + q) * H + c0 + ct*16];
        }

        for (int j = 0; j < T; ++j) {
            f32x4 acc[4][2];
#pragma unroll
            for (int rt = 0; rt < 4; ++rt) { acc[rt][0] = (f32x4)(0.f); acc[rt][1] = (f32x4)(0.f); }

            if (j > 0) MMPHASE(0, bfL, acc);        // own-left from persistent LDS

            if (i > 0) {
                if (tid == 0) pollone(&f0[((i-1)*T + j)*FPAD]);
                __syncthreads();                    // P: flag seen by all
                STAGE(32768, OPTR(0, i-1, j, 0));
            }
            __syncthreads();                        // B1: staging visible / phase-A done

            if (i > 0) MMPHASE(32768, bfT, acc);

            // ---- hx (critical chain) ----
            float recs[32];
            float* ox = OPTR(0, i, j, 0);
#pragma unroll
            for (int rt = 0; rt < 4; ++rt)
#pragma unroll
                for (int ct = 0; ct < 2; ++ct) {
                    const float bb = ct ? bb1 : bb0;
                    const int col = c0 + ct*16;
#pragma unroll
                    for (int q = 0; q < 4; ++q) {
                        int idx = (rt*4+q)*2+ct;
                        int r = rt*16 + hi*4 + q;
                        float rec = acc[rt][ct][q] + bb;
                        recs[idx] = rec;
                        float hx = tanh_fast(b2f(xwr[idx]) + rec);
                        __hip_atomic_store(&ox[r*H + col], hx, __ATOMIC_RELAXED, __HIP_MEMORY_SCOPE_AGENT);
                        *(unsigned short*)(lds + r*512 + ((col*2) ^ ((r&7)<<4))) = f2b(hx);
                    }
                }
            asm volatile("s_waitcnt vmcnt(0)" ::: "memory");
            __syncthreads();                        // B2
            if (tid == 0)
                __hip_atomic_store(&f0[(i*T + j)*FPAD], 1, __ATOMIC_RELAXED, __HIP_MEMORY_SCOPE_AGENT);

            // ---- hy (off-chain) ----
            {
                unsigned short ywr[32];
                const unsigned short* ywp = tywb + (size_t)j * CH_;
#pragma unroll
                for (int rt = 0; rt < 4; ++rt)
#pragma unroll
                    for (int ct = 0; ct < 2; ++ct)
#pragma unroll
                        for (int q = 0; q < 4; ++q)
                            ywr[(rt*4+q)*2+ct] = ywp[(size_t)(rt*16 + hi*4 + q) * H + c0 + ct*16];
                float* oy = OPTR(0, i, j, 1);
#pragma unroll
                for (int rt = 0; rt < 4; ++rt)
#pragma unroll
                    for (int ct = 0; ct < 2; ++ct) {
                        const int col = c0 + ct*16;
#pragma unroll
                        for (int q = 0; q < 4; ++q) {
                            int idx = (rt*4+q)*2+ct;
                            int r = rt*16 + hi*4 + q;
                            float hy = tanh_fast(b2f(ywr[idx]) + recs[idx]);
                            __hip_atomic_store(&oy[r*H + col], hy, __ATOMIC_RELAXED, __HIP_MEMORY_SCOPE_AGENT);
                            *(unsigned short*)(lds + 32768 + r*512 + ((col*2) ^ ((r&7)<<4))) = f2b(hy);
                        }
                    }
            }
            __syncthreads();                        // B3: hy bf16 in LDS (top region reuse)

            // ---- fold d1's input projections: xw1 = hx0@W1, yw1 = hy0@W1 ----
            {
                uintptr_t bsw_o = (uintptr_t)Bsw;
                asm volatile("" : "+v"(bsw_o));     // defeat LICM (keep bW streamed)
                const unsigned short* mW = (const unsigned short*)bsw_o + (size_t)4*MSZ;
                f32x4 px[4][2], py[4][2];
#pragma unroll
                for (int rt = 0; rt < 4; ++rt) { px[rt][0]=(f32x4)(0.f); px[rt][1]=(f32x4)(0.f);
                                                 py[rt][0]=(f32x4)(0.f); py[rt][1]=(f32x4)(0.f); }
#pragma unroll
                for (int kt = 0; kt < 8; ++kt) {
                    s16x8 ax0 = AFRAG(0, 0, kt), ax1 = AFRAG(0, 1, kt);
                    s16x8 ax2 = AFRAG(0, 2, kt), ax3 = AFRAG(0, 3, kt);
                    s16x8 ay0 = AFRAG(32768, 0, kt), ay1 = AFRAG(32768, 1, kt);
                    s16x8 ay2 = AFRAG(32768, 2, kt), ay3 = AFRAG(32768, 3, kt);
#pragma unroll
                    for (int ct = 0; ct < 2; ++ct) {
                        s16x8 bW = *(const s16x8*)(mW + (kt * H + c0 + ct*16) * 32 + kk0);
                        px[0][ct] = __builtin_amdgcn_mfma_f32_16x16x32_bf16(ax0, bW, px[0][ct], 0, 0, 0);
                        px[1][ct] = __builtin_amdgcn_mfma_f32_16x16x32_bf16(ax1, bW, px[1][ct], 0, 0, 0);
                        px[2][ct] = __builtin_amdgcn_mfma_f32_16x16x32_bf16(ax2, bW, px[2][ct], 0, 0, 0);
                        px[3][ct] = __builtin_amdgcn_mfma_f32_16x16x32_bf16(ax3, bW, px[3][ct], 0, 0, 0);
                        py[0][ct] = __builtin_amdgcn_mfma_f32_16x16x32_bf16(ay0, bW, py[0][ct], 0, 0, 0);
                        py[1][ct] = __builtin_amdgcn_mfma_f32_16x16x32_bf16(ay1, bW, py[1][ct], 0, 0, 0);
                        py[2][ct] = __builtin_amdgcn_mfma_f32_16x16x32_bf16(ay2, bW, py[2][ct], 0, 0, 0);
                        py[3][ct] = __builtin_amdgcn_mfma_f32_16x16x32_bf16(ay3, bW, py[3][ct], 0, 0, 0);
                    }
                }
                // stash into d1's output slots (d1 overwrites after reading)
                float* p0 = OPTR(1, i, j, 0);
                float* p1 = OPTR(1, i, j, 1);
#pragma unroll
                for (int rt = 0; rt < 4; ++rt)
#pragma unroll
                    for (int ct = 0; ct < 2; ++ct) {
                        const int col = c0 + ct*16;
#pragma unroll
                        for (int q = 0; q < 4; ++q) {
                            int r = rt*16 + hi*4 + q;
                            __hip_atomic_store(&p0[r*H + col], px[rt][ct][q], __ATOMIC_RELAXED, __HIP_MEMORY_SCOPE_AGENT);
                            __hip_atomic_store(&p1[r*H + col], py[rt][ct][q], __ATOMIC_RELAXED, __HIP_MEMORY_SCOPE_AGENT);
                        }
                    }
            }
            asm volatile("s_waitcnt vmcnt(0)" ::: "memory");
            __syncthreads();                        // B4: top region free for next j
            if (tid == 0)
                __hip_atomic_store(&g0[(i*T + j)*FPAD], 1, __ATOMIC_RELAXED, __HIP_MEMORY_SCOPE_AGENT);
        }
    } else {
        s16x8 bfT[8][2], bfL[8][2];
#pragma unroll
        for (int kt = 0; kt < 8; ++kt)
#pragma unroll
            for (int ct = 0; ct < 2; ++ct) {
                int o = (kt * H + c0 + ct*16) * 32 + kk0;
                bfT[kt][ct] = *(const s16x8*)(Bsw + (size_t)2*MSZ + o);
                bfL[kt][ct] = *(const s16x8*)(Bsw + (size_t)3*MSZ + o);
            }
        const float bb0 = bvec[H + c0], bb1 = bvec[H + c0 + 16];

        for (int j = 0; j < T; ++j) {
            f32x4 acc[4][2];
#pragma unroll
            for (int rt = 0; rt < 4; ++rt) { acc[rt][0] = (f32x4)(0.f); acc[rt][1] = (f32x4)(0.f); }

            if (j > 0) MMPHASE(0, bfL, acc);        // own-left from persistent LDS

            if (tid == 0) {
                pollone(&g0[(i*T + j)*FPAD]);
                if (i > 0) pollone(&f1[((i-1)*T + j)*FPAD]);
            }
            __syncthreads();                        // P

            // lane-private xw1 loads (same addrs this lane later overwrites)
            float xw1r[32];
            {
                const float* p0s = OPTR(1, i, j, 0);
#pragma unroll
                for (int rt = 0; rt < 4; ++rt)
#pragma unroll
                    for (int ct = 0; ct < 2; ++ct)
#pragma unroll
                        for (int q = 0; q < 4; ++q)
                            xw1r[(rt*4+q)*2+ct] = p0s[(rt*16 + hi*4 + q)*H + c0 + ct*16];
            }
            if (i > 0) STAGE(32768, OPTR(1, i-1, j, 0));
            __syncthreads();                        // B1

            if (i > 0) MMPHASE(32768, bfT, acc);

            // ---- hx1 (critical chain) ----
            float recs[32];
            float* ox = OPTR(1, i, j, 0);
#pragma unroll
            for (int rt = 0; rt < 4; ++rt)
#pragma unroll
                for (int ct = 0; ct < 2; ++ct) {
                    const float bb = ct ? bb1 : bb0;
                    const int col = c0 + ct*16;
#pragma unroll
                    for (int q = 0; q < 4; ++q) {
                        int idx = (rt*4+q)*2+ct;
                        int r = rt*16 + hi*4 + q;
                        float rec = acc[rt][ct][q] + bb;
                        recs[idx] = rec;
                        float hx = tanh_fast(xw1r[idx] + rec);
                        __hip_atomic_store(&ox[r*H + col], hx, __ATOMIC_RELAXED, __HIP_MEMORY_SCOPE_AGENT);
                        *(unsigned short*)(lds + r*512 + ((col*2) ^ ((r&7)<<4))) = f2b(hx);
                    }
                }
            asm volatile("s_waitcnt vmcnt(0)" ::: "memory");
            __syncthreads();                        // B2
            if (tid == 0)
                __hip_atomic_store(&f1[(i*T + j)*FPAD], 1, __ATOMIC_RELAXED, __HIP_MEMORY_SCOPE_AGENT);

            // ---- hy1 (off-chain; lane-private read-then-overwrite) ----
            {
                float* p1 = OPTR(1, i, j, 1);
#pragma unroll
                for (int rt = 0; rt < 4; ++rt)
#pragma unroll
                    for (int ct = 0; ct < 2; ++ct) {
                        const int col = c0 + ct*16;
#pragma unroll
                        for (int q = 0; q < 4; ++q) {
                            int idx = (rt*4+q)*2+ct;
                            int r = rt*16 + hi*4 + q;
                            float yw1 = p1[r*H + col];
                            float hy = tanh_fast(yw1 + recs[idx]);
                            __hip_atomic_store(&p1[r*H + col], hy, __ATOMIC_RELAXED, __HIP_MEMORY_SCOPE_AGENT);
                        }
                    }
            }
        }
    }
#undef OPTR
#undef STAGE
#undef AFRAG
#undef MMPHASE
}

// =================== staged fallback (round-2 structure) ===================
__global__ __launch_bounds__(64) void stage_kernel(
    const unsigned short* __restrict__ Bsw,
    const unsigned short* __restrict__ sxwb,
    const unsigned short* __restrict__ tywb,
    const float* __restrict__ bvec,
    float* __restrict__ out, int v)
{
    const int lane = threadIdx.x;
    const int cellid = blockIdx.x >> 2;
    const int stripe = blockIdx.x & 3;

    int ilo0 = (v > T-1) ? v-(T-1) : 0, ihi0 = (v < S-1) ? v : S-1;
    int n0 = (v <= S+T-2) ? (ihi0 - ilo0 + 1) : 0;
    if (n0 < 0) n0 = 0;
    int w1 = v - 1;
    int ilo1 = (w1 > T-1) ? w1-(T-1) : 0;

    int d, i, j;
    if (cellid < n0) { d = 0; i = ilo0 + cellid; j = v - i; }
    else             { d = 1; int q = cellid - n0; i = ilo1 + q; j = w1 - i; }

    const int r0   = stripe * 16;
    const int arow = r0 + (lane & 15);
    const int kk0  = (lane >> 4) * 8;
    const int colq = lane & 15;
    const int rowq = r0 + ((lane >> 4) << 2);

#define OUTB(dd,ii,jj,cc) (out + ((((size_t)(dd)*S + (ii))*T + (jj))*2 + (cc)) * (size_t)(B*H))

    if (d == 0) {
        f32x4 acc[16];
#pragma unroll
        for (int t = 0; t < 16; ++t) acc[t] = (f32x4)(0.f);
        if (i > 0) {
            const float* topM = OUTB(0, i-1, j, 0);
            const unsigned short* Bt = Bsw + 0*MSZ;
            for (int kt = 0; kt < 8; ++kt) {
                s16x8 a = make_afrag(topM, arow, kt*32 + kk0);
                const unsigned short* bp = Bt + (kt*H + colq)*32 + kk0;
#pragma unroll
                for (int ct = 0; ct < 16; ++ct)
                    acc[ct] = __builtin_amdgcn_mfma_f32_16x16x32_bf16(a, *(const s16x8*)(bp + ct*512), acc[ct], 0, 0, 0);
            }
        }
        if (j > 0) {
            const float* lftM = OUTB(0, i, j-1, 0);
            const unsigned short* Bl = Bsw + 1*MSZ;
            for (int kt = 0; kt < 8; ++kt) {
                s16x8 a = make_afrag(lftM, arow, kt*32 + kk0);
                const unsigned short* bp = Bl + (kt*H + colq)*32 + kk0;
#pragma unroll
                for (int ct = 0; ct < 16; ++ct)
                    acc[ct] = __builtin_amdgcn_mfma_f32_16x16x32_bf16(a, *(const s16x8*)(bp + ct*512), acc[ct], 0, 0, 0);
            }
        }
        const unsigned short* xwp = sxwb + (size_t)i * B * H;
        const unsigned short* ywp = tywb + (size_t)j * B * H;
        float* ox = OUTB(0, i, j, 0);
        float* oy = OUTB(0, i, j, 1);
#pragma unroll
        for (int ct = 0; ct < 16; ++ct) {
            int col = ct*16 + colq;
            float bc = bvec[col];
#pragma unroll
            for (int q = 0; q < 4; ++q) {
                int row = rowq + q;
                float rec = acc[ct][q] + bc;
                ox[row*H + col] = tanh_fast(b2f(xwp[row*H + col]) + rec);
                oy[row*H + col] = tanh_fast(b2f(ywp[row*H + col]) + rec);
            }
        }
    } else {
        const float* hx0 = OUTB(0, i, j, 0);
        const float* hy0 = OUTB(0, i, j, 1);
        const float* topM = (i > 0) ? OUTB(1, i-1, j, 0) : (const float*)0;
        const float* lftM = (j > 0) ? OUTB(1, i, j-1, 0) : (const float*)0;
        const unsigned short* BU1t = Bsw + 2*MSZ;
        const unsigned short* BU1l = Bsw + 3*MSZ;
        const unsigned short* BW1  = Bsw + 4*MSZ;
        float* ox = OUTB(1, i, j, 0);
        float* oy = OUTB(1, i, j, 1);

        for (int halfc = 0; halfc < 2; ++halfc) {
            f32x4 arr[8], axx[8], ayy[8];
#pragma unroll
            for (int t = 0; t < 8; ++t) { arr[t]=(f32x4)(0.f); axx[t]=(f32x4)(0.f); ayy[t]=(f32x4)(0.f); }
            const int bbase = halfc*4096 + colq*32 + kk0;

            for (int kt = 0; kt < 8; ++kt) {
                const int k0 = kt*32 + kk0;
                const int bofs = kt*H*32 + bbase;
                if (topM) {
                    s16x8 a = make_afrag(topM, arow, k0);
#pragma unroll
                    for (int ct = 0; ct < 8; ++ct)
                        arr[ct] = __builtin_amdgcn_mfma_f32_16x16x32_bf16(a, *(const s16x8*)(BU1t + bofs + ct*512), arr[ct], 0, 0, 0);
                }
                if (lftM) {
                    s16x8 a = make_afrag(lftM, arow, k0);
#pragma unroll
                    for (int ct = 0; ct < 8; ++ct)
                        arr[ct] = __builtin_amdgcn_mfma_f32_16x16x32_bf16(a, *(const s16x8*)(BU1l + bofs + ct*512), arr[ct], 0, 0, 0);
                }
                {
                    s16x8 a = make_afrag(hx0, arow, k0);
#pragma unroll
                    for (int ct = 0; ct < 8; ++ct)
                        axx[ct] = __builtin_amdgcn_mfma_f32_16x16x32_bf16(a, *(const s16x8*)(BW1 + bofs + ct*512), axx[ct], 0, 0, 0);
                }
                {
                    s16x8 a = make_afrag(hy0, arow, k0);
#pragma unroll
                    for (int ct = 0; ct < 8; ++ct)
                        ayy[ct] = __builtin_amdgcn_mfma_f32_16x16x32_bf16(a, *(const s16x8*)(BW1 + bofs + ct*512), ayy[ct], 0, 0, 0);
                }
            }
#pragma unroll
            for (int ct = 0; ct < 8; ++ct) {
                int col = halfc*128 + ct*16 + colq;
                float bc = bvec[H + col];
#pragma unroll
                for (int q = 0; q < 4; ++q) {
                    int row = rowq + q;
                    float rec = arr[ct][q] + bc;
                    ox[row*H + col] = tanh_fast(axx[ct][q] + rec);
                    oy[row*H + col] = tanh_fast(ayy[ct][q] + rec);
                }
            }
        }
    }
#undef OUTB
}

// ============================ host launcher ================================
extern "C" void kernel_launch(void* const* d_in, const int* in_sizes, int n_in,
                              void* d_out, int out_size, void* d_ws, size_t ws_size,
                              hipStream_t stream)
{
    const float* src = (const float*)d_in[0];
    const float* trg = (const float*)d_in[1];
    const float* W   = (const float*)d_in[2];
    const float* U   = (const float*)d_in[3];
    const float* b   = (const float*)d_in[4];
    float* out = (float*)d_out;

    const int nflags = 3 * S * T * FPAD;
    const size_t need_stage   = (size_t)5*MSZ*2 + (size_t)2*S*B*H*2;
    const size_t need_persist = need_stage + (size_t)nflags*sizeof(int);

    unsigned short* Bsw  = (unsigned short*)d_ws;
    unsigned short* sxwb = Bsw + (size_t)5*MSZ;
    unsigned short* tywb = sxwb + (size_t)S*B*H;
    int* flags = (int*)(tywb + (size_t)S*B*H);

    prep_kernel<<<(5*MSZ + 255)/256, 256, 0, stream>>>(U, W, Bsw);
    proj0b_kernel<<<2*S*B/ROWSP, 256, 0, stream>>>(src, trg, W, sxwb, tywb);

    if (ws_size >= need_persist) {
        zeroflags_kernel<<<(nflags + 255)/256, 256, 0, stream>>>(flags, nflags);
        grid_kernel<<<64, 512, 0, stream>>>(Bsw, sxwb, tywb, b, out, flags);
        return;
    }

    // -------- staged fallback --------
    for (int v = 0; v < S + T; ++v) {
        int ilo0 = (v > T-1) ? v-(T-1) : 0, ihi0 = (v < S-1) ? v : S-1;
        int n0 = (v <= S+T-2) ? (ihi0 - ilo0 + 1) : 0;
        if (n0 < 0) n0 = 0;
        int n1 = 0;
        int w1 = v - 1;
        if (w1 >= 0) {
            int ilo1 = (w1 > T-1) ? w1-(T-1) : 0, ihi1 = (w1 < S-1) ? w1 : S-1;
            n1 = ihi1 - ilo1 + 1;
        }
        stage_kernel<<<4*(n0+n1), 64, 0, stream>>>(Bsw, sxwb, tywb, b, out, v);
    }
}